// Round 1
// baseline (227.883 us; speedup 1.0000x reference)
//
#include <hip/hip_runtime.h>
#include <cstdint>
#include <cstddef>

#define D_MODEL 1024
#define NHEAD   16
#define DKH     64
#define BATCH   2
#define SEQ     2048
#define BL      (BATCH*SEQ)

typedef unsigned short u16;
typedef unsigned int   u32;
typedef __bf16 bf16_t;
typedef bf16_t bf16x8 __attribute__((ext_vector_type(8)));
typedef u16    u16x8  __attribute__((ext_vector_type(8)));
typedef float  f32x4  __attribute__((ext_vector_type(4)));

__device__ __forceinline__ u16 f2bf(float f) {
  u32 u = __builtin_bit_cast(u32, f);
  u32 r = (u + 0x7FFFu + ((u >> 16) & 1u)) >> 16;
  return (u16)r;
}
__device__ __forceinline__ float bf2f(u16 h) {
  u32 u = ((u32)h) << 16;
  return __builtin_bit_cast(float, u);
}
__device__ __forceinline__ bf16x8 ldb8(const u16* p) {
  return __builtin_bit_cast(bf16x8, *(const u16x8*)p);
}
__device__ __forceinline__ void gl_lds16(const u16* g, u16* l) {
  __builtin_amdgcn_global_load_lds((const __attribute__((address_space(1))) void*)g,
                                   (__attribute__((address_space(3))) void*)l, 16, 0, 0);
}
#define MFMA16x16x32(a,b,c) __builtin_amdgcn_mfma_f32_16x16x32_bf16((a),(b),(c),0,0,0)

// ---------------- fp32 -> bf16 converts ----------------
__global__ void __launch_bounds__(256) cvt1_kernel(const float* __restrict__ in, u16* __restrict__ out, int n8) {
  int i = blockIdx.x * 256 + threadIdx.x;
  if (i >= n8) return;
  float4 a = ((const float4*)in)[2*i];
  float4 b = ((const float4*)in)[2*i+1];
  u16x8 o;
  o[0]=f2bf(a.x); o[1]=f2bf(a.y); o[2]=f2bf(a.z); o[3]=f2bf(a.w);
  o[4]=f2bf(b.x); o[5]=f2bf(b.y); o[6]=f2bf(b.z); o[7]=f2bf(b.w);
  ((u16x8*)out)[i] = o;
}

__global__ void __launch_bounds__(256) cvt4_kernel(const float* __restrict__ i0, const float* __restrict__ i1,
                                                   const float* __restrict__ i2, const float* __restrict__ i3,
                                                   u16* __restrict__ o0, u16* __restrict__ o1,
                                                   u16* __restrict__ o2, u16* __restrict__ o3, int n8) {
  int i = blockIdx.x * 256 + threadIdx.x;
  if (i >= n8) return;
  const float* in = (blockIdx.y == 0) ? i0 : (blockIdx.y == 1) ? i1 : (blockIdx.y == 2) ? i2 : i3;
  u16*        out = (blockIdx.y == 0) ? o0 : (blockIdx.y == 1) ? o1 : (blockIdx.y == 2) ? o2 : o3;
  float4 a = ((const float4*)in)[2*i];
  float4 b = ((const float4*)in)[2*i+1];
  u16x8 o;
  o[0]=f2bf(a.x); o[1]=f2bf(a.y); o[2]=f2bf(a.z); o[3]=f2bf(a.w);
  o[4]=f2bf(b.x); o[5]=f2bf(b.y); o[6]=f2bf(b.z); o[7]=f2bf(b.w);
  ((u16x8*)out)[i] = o;
}

// ---------------- GEMM: C[M,N] = A[M,K] * W[N,K]^T (m97-style 128x128 tile) ----------------
template<bool F32OUT>
__device__ __forceinline__ void gemm_body(const u16* __restrict__ A, const u16* __restrict__ W,
                                          void* __restrict__ Cv, int M, int N, int K) {
  __shared__ u16 Als[128*64];
  __shared__ u16 Bls[128*64];
  const int tid = threadIdx.x, lane = tid & 63, w = tid >> 6;
  const int wr = w >> 1, wc = w & 1;
  const int lr = lane & 15, lg = lane >> 4;
  const int m0 = blockIdx.x * 128, n0 = blockIdx.y * 128;
  f32x4 acc[4][4] = {};
  const int srow = lane >> 3;        // 0..7 row within 8-row stage chunk
  const int scol = (lane & 7) * 8;   // elem col within 64
  for (int k0 = 0; k0 < K; k0 += 64) {
    __syncthreads();
    #pragma unroll
    for (int c = 0; c < 4; ++c) {
      const int rb = w*32 + c*8;
      const u16* ga = A + (size_t)(m0 + rb + srow)*K + k0 + scol;
      const u16* gb = W + (size_t)(n0 + rb + srow)*K + k0 + scol;
      gl_lds16(ga, &Als[rb*64]);
      gl_lds16(gb, &Bls[rb*64]);
    }
    __syncthreads();
    #pragma unroll
    for (int ks = 0; ks < 2; ++ks) {
      bf16x8 am[4], bn[4];
      #pragma unroll
      for (int f = 0; f < 4; ++f) {
        am[f] = ldb8(&Als[(wr*64 + f*16 + lr)*64 + ks*32 + lg*8]);
        bn[f] = ldb8(&Bls[(wc*64 + f*16 + lr)*64 + ks*32 + lg*8]);
      }
      #pragma unroll
      for (int fm = 0; fm < 4; ++fm)
        #pragma unroll
        for (int fn = 0; fn < 4; ++fn)
          acc[fm][fn] = MFMA16x16x32(am[fm], bn[fn], acc[fm][fn]);
    }
  }
  #pragma unroll
  for (int fm = 0; fm < 4; ++fm)
    #pragma unroll
    for (int fn = 0; fn < 4; ++fn)
      #pragma unroll
      for (int r = 0; r < 4; ++r) {
        const int row = m0 + wr*64 + fm*16 + lg*4 + r;
        const int col = n0 + wc*64 + fn*16 + lr;
        if constexpr (F32OUT) ((float*)Cv)[(size_t)row*N + col] = acc[fm][fn][r];
        else                  ((u16*)Cv)[(size_t)row*N + col] = f2bf(acc[fm][fn][r]);
      }
}

__global__ void __launch_bounds__(256) gemm_qkv_kernel(const u16* __restrict__ X,
    const u16* __restrict__ Wq, const u16* __restrict__ Wk, const u16* __restrict__ Wv,
    u16* __restrict__ Qo, u16* __restrict__ Ko, u16* __restrict__ Vo) {
  const u16* W = (blockIdx.z == 0) ? Wq : (blockIdx.z == 1) ? Wk : Wv;
  u16*       C = (blockIdx.z == 0) ? Qo : (blockIdx.z == 1) ? Ko : Vo;
  gemm_body<false>(X, W, C, BL, D_MODEL, D_MODEL);
}

__global__ void __launch_bounds__(256) gemm_out_kernel(const u16* __restrict__ A, const u16* __restrict__ W,
                                                       float* __restrict__ C) {
  gemm_body<true>(A, W, C, BL, D_MODEL, D_MODEL);
}

// ---------------- RoPE (in-place on bf16 Q,K), folds 1/sqrt(dk)=0.125 into Q ----------------
__global__ void __launch_bounds__(256) rope_kernel(u16* __restrict__ Q, u16* __restrict__ K,
                                                   const int* __restrict__ pos) {
  int t = blockIdx.x * 256 + threadIdx.x;   // over BL*512 pairs (shared by Q and K)
  int i  = t & 31;          // freq index 0..31
  int h  = (t >> 5) & 15;   // head
  int bl = t >> 9;          // b*L + l
  float fr = exp2f(-(float)i * 0.41524101186092f);   // 10000^(-i/32)
  float ang = (float)pos[bl] * fr;
  float sv, cv;
  sincosf(ang, &sv, &cv);
  size_t base = (size_t)bl * D_MODEL + h * DKH + 2*i;
  u32 qv = *(u32*)&Q[base];
  float qe = bf2f((u16)(qv & 0xFFFFu)), qo = bf2f((u16)(qv >> 16));
  float re = (qe*cv - qo*sv) * 0.125f;
  float ro = (qe*sv + qo*cv) * 0.125f;
  *(u32*)&Q[base] = (u32)f2bf(re) | ((u32)f2bf(ro) << 16);
  u32 kw = *(u32*)&K[base];
  float ke = bf2f((u16)(kw & 0xFFFFu)), ko = bf2f((u16)(kw >> 16));
  *(u32*)&K[base] = (u32)f2bf(ke*cv - ko*sv) | ((u32)f2bf(ke*sv + ko*cv) << 16);
}

// ---------------- causal flash attention, 4 waves/block, Qtile=64, KVtile=64 ----------------
#define VSTR 72

__global__ void __launch_bounds__(256) attn_kernel(const u16* __restrict__ Q, const u16* __restrict__ K,
                                                   const u16* __restrict__ V, u16* __restrict__ O) {
  __shared__ u16 Kls[64*VSTR];
  __shared__ u16 Vt[64*VSTR];
  __shared__ u16 Pls[4][16*VSTR];
  const int tid = threadIdx.x, lane = tid & 63, w = tid >> 6;
  const int lr = lane & 15, lg = lane >> 4;
  const int bh = blockIdx.y, b = bh >> 4, h = bh & 15;
  const int q0 = blockIdx.x * 64;
  const size_t headoff = (size_t)b * SEQ * D_MODEL + (size_t)h * DKH;
  const u16* Qb = Q + headoff;
  const u16* Kb = K + headoff;
  const u16* Vb = V + headoff;
  bf16x8 qf[2];
  {
    int qrow = q0 + w*16 + lr;
    qf[0] = ldb8(Qb + (size_t)qrow*D_MODEL + lg*8);
    qf[1] = ldb8(Qb + (size_t)qrow*D_MODEL + 32 + lg*8);
  }
  f32x4 oacc[4] = {};
  float mrun[4], lrun[4];
  #pragma unroll
  for (int r = 0; r < 4; ++r) { mrun[r] = -1e30f; lrun[r] = 0.0f; }
  const int wave_qmax = q0 + w*16 + 15;
  const int ntiles = blockIdx.x + 1;
  for (int t = 0; t < ntiles; ++t) {
    const int kv0 = t * 64;
    __syncthreads();
    {  // stage K (row-padded) and V^T
      int r  = tid >> 2;
      int cs = (tid & 3) * 16;
      const u16* kg = Kb + (size_t)(kv0 + r)*D_MODEL + cs;
      const u16* vg = Vb + (size_t)(kv0 + r)*D_MODEL + cs;
      *(u16x8*)&Kls[r*VSTR + cs]     = *(const u16x8*)kg;
      *(u16x8*)&Kls[r*VSTR + cs + 8] = *(const u16x8*)(kg + 8);
      u16x8 v0 = *(const u16x8*)vg;
      u16x8 v1 = *(const u16x8*)(vg + 8);
      #pragma unroll
      for (int j = 0; j < 8; ++j) Vt[(cs + j)*VSTR + r] = v0[j];
      #pragma unroll
      for (int j = 0; j < 8; ++j) Vt[(cs + 8 + j)*VSTR + r] = v1[j];
    }
    __syncthreads();
    if (kv0 > wave_qmax) continue;   // fully-masked tile for this wave (both barriers already passed)
    f32x4 s[4] = {};
    #pragma unroll
    for (int f = 0; f < 4; ++f) {
      bf16x8 kf0 = ldb8(&Kls[(f*16 + lr)*VSTR + lg*8]);
      bf16x8 kf1 = ldb8(&Kls[(f*16 + lr)*VSTR + 32 + lg*8]);
      s[f] = MFMA16x16x32(qf[0], kf0, s[f]);
      s[f] = MFMA16x16x32(qf[1], kf1, s[f]);
    }
    if (kv0 + 63 > q0 + w*16) {   // diagonal tile: causal mask
      #pragma unroll
      for (int f = 0; f < 4; ++f) {
        int kvc = kv0 + f*16 + lr;
        #pragma unroll
        for (int r = 0; r < 4; ++r) {
          int qr = q0 + w*16 + lg*4 + r;
          if (kvc > qr) s[f][r] = -1e30f;
        }
      }
    }
    // online softmax (row stats live in the 16-lane group)
    #pragma unroll
    for (int r = 0; r < 4; ++r) {
      float mx = fmaxf(fmaxf(s[0][r], s[1][r]), fmaxf(s[2][r], s[3][r]));
      mx = fmaxf(mx, __shfl_xor(mx, 1, 64));
      mx = fmaxf(mx, __shfl_xor(mx, 2, 64));
      mx = fmaxf(mx, __shfl_xor(mx, 4, 64));
      mx = fmaxf(mx, __shfl_xor(mx, 8, 64));
      float mnew = fmaxf(mrun[r], mx);
      float alpha = __expf(mrun[r] - mnew);
      mrun[r] = mnew;
      float ps = 0.f;
      #pragma unroll
      for (int f = 0; f < 4; ++f) { float p = __expf(s[f][r] - mnew); s[f][r] = p; ps += p; }
      ps += __shfl_xor(ps, 1, 64);
      ps += __shfl_xor(ps, 2, 64);
      ps += __shfl_xor(ps, 4, 64);
      ps += __shfl_xor(ps, 8, 64);
      lrun[r] = lrun[r]*alpha + ps;
      #pragma unroll
      for (int fd = 0; fd < 4; ++fd) oacc[fd][r] *= alpha;
    }
    // P -> per-wave LDS (D-layout) then re-read in A-layout
    #pragma unroll
    for (int f = 0; f < 4; ++f)
      #pragma unroll
      for (int r = 0; r < 4; ++r)
        Pls[w][(lg*4 + r)*VSTR + f*16 + lr] = f2bf(s[f][r]);
    bf16x8 pf0 = ldb8(&Pls[w][lr*VSTR + lg*8]);
    bf16x8 pf1 = ldb8(&Pls[w][lr*VSTR + 32 + lg*8]);
    #pragma unroll
    for (int fd = 0; fd < 4; ++fd) {
      bf16x8 vf0 = ldb8(&Vt[(fd*16 + lr)*VSTR + lg*8]);
      bf16x8 vf1 = ldb8(&Vt[(fd*16 + lr)*VSTR + 32 + lg*8]);
      oacc[fd] = MFMA16x16x32(pf0, vf0, oacc[fd]);
      oacc[fd] = MFMA16x16x32(pf1, vf1, oacc[fd]);
    }
  }
  u16* Ob = O + headoff;
  #pragma unroll
  for (int fd = 0; fd < 4; ++fd)
    #pragma unroll
    for (int r = 0; r < 4; ++r) {
      int row = q0 + w*16 + lg*4 + r;
      Ob[(size_t)row*D_MODEL + fd*16 + lr] = f2bf(oacc[fd][r] / lrun[r]);
    }
}

// ---------------- launch ----------------
extern "C" void kernel_launch(void* const* d_in, const int* in_sizes, int n_in,
                              void* d_out, int out_size, void* d_ws, size_t ws_size,
                              hipStream_t stream) {
  const float* x  = (const float*)d_in[0];
  const int* pos  = (const int*)d_in[1];
  const float* WQ = (const float*)d_in[2];
  const float* WK = (const float*)d_in[3];
  const float* WV = (const float*)d_in[4];
  const float* WO = (const float*)d_in[5];
  u16* ws = (u16*)d_ws;
  const size_t NX = (size_t)BL * D_MODEL;       // 4M elems
  const size_t NW = (size_t)D_MODEL * D_MODEL;  // 1M elems
  u16* xb  = ws;
  u16* wqb = xb  + NX;
  u16* wkb = wqb + NW;
  u16* wvb = wkb + NW;
  u16* wob = wvb + NW;
  u16* qb  = wob + NW;
  u16* kb  = qb  + NX;
  u16* vb  = kb  + NX;
  u16* ab  = vb  + NX;   // total 24M u16 = 48 MB

  cvt1_kernel<<<dim3((unsigned)(NX/8/256)), 256, 0, stream>>>(x, xb, (int)(NX/8));
  cvt4_kernel<<<dim3((unsigned)(NW/8/256), 4), 256, 0, stream>>>(WQ, WK, WV, WO, wqb, wkb, wvb, wob, (int)(NW/8));
  gemm_qkv_kernel<<<dim3(BL/128, D_MODEL/128, 3), 256, 0, stream>>>(xb, wqb, wkb, wvb, qb, kb, vb);
  rope_kernel<<<dim3(BL*512/256), 256, 0, stream>>>(qb, kb, pos);
  attn_kernel<<<dim3(SEQ/64, BATCH*NHEAD), 256, 0, stream>>>(qb, kb, vb, ab);
  gemm_out_kernel<<<dim3(BL/128, D_MODEL/128), 256, 0, stream>>>(ab, wob, (float*)d_out);
}

// Round 2
// 180.735 us; speedup vs baseline: 1.2609x; 1.2609x over previous
//
#include <hip/hip_runtime.h>
#include <cstdint>
#include <cstddef>

#define D_MODEL 1024
#define NHEAD   16
#define DKH     64
#define BATCH   2
#define SEQ     2048
#define BL      (BATCH*SEQ)

typedef unsigned short u16;
typedef unsigned int   u32;
typedef __bf16 bf16_t;
typedef bf16_t bf16x8 __attribute__((ext_vector_type(8)));
typedef u16    u16x8  __attribute__((ext_vector_type(8)));
typedef u32    u32x4  __attribute__((ext_vector_type(4)));
typedef float  f32x4  __attribute__((ext_vector_type(4)));
typedef float  f32x16 __attribute__((ext_vector_type(16)));

__device__ __forceinline__ u16 f2bf(float f) {
  u32 u = __builtin_bit_cast(u32, f);
  u32 r = (u + 0x7FFFu + ((u >> 16) & 1u)) >> 16;
  return (u16)r;
}
__device__ __forceinline__ float bf2f(u16 h) {
  u32 u = ((u32)h) << 16;
  return __builtin_bit_cast(float, u);
}
__device__ __forceinline__ bf16x8 ldb8(const u16* p) {
  return __builtin_bit_cast(bf16x8, *(const u16x8*)p);
}
__device__ __forceinline__ void gl_lds16(const u16* g, u16* l) {
  __builtin_amdgcn_global_load_lds((const __attribute__((address_space(1))) void*)g,
                                   (__attribute__((address_space(3))) void*)l, 16, 0, 0);
}
#define MFMA16x16x32(a,b,c) __builtin_amdgcn_mfma_f32_16x16x32_bf16((a),(b),(c),0,0,0)
#define MFMA32x32x16(a,b,c) __builtin_amdgcn_mfma_f32_32x32x16_bf16((a),(b),(c),0,0,0)

// ---------------- fp32 -> bf16 converts ----------------
__global__ void __launch_bounds__(256) cvt1_kernel(const float* __restrict__ in, u16* __restrict__ out, int n8) {
  int i = blockIdx.x * 256 + threadIdx.x;
  if (i >= n8) return;
  float4 a = ((const float4*)in)[2*i];
  float4 b = ((const float4*)in)[2*i+1];
  u16x8 o;
  o[0]=f2bf(a.x); o[1]=f2bf(a.y); o[2]=f2bf(a.z); o[3]=f2bf(a.w);
  o[4]=f2bf(b.x); o[5]=f2bf(b.y); o[6]=f2bf(b.z); o[7]=f2bf(b.w);
  ((u16x8*)out)[i] = o;
}

__global__ void __launch_bounds__(256) cvt4_kernel(const float* __restrict__ i0, const float* __restrict__ i1,
                                                   const float* __restrict__ i2, const float* __restrict__ i3,
                                                   u16* __restrict__ o0, u16* __restrict__ o1,
                                                   u16* __restrict__ o2, u16* __restrict__ o3, int n8) {
  int i = blockIdx.x * 256 + threadIdx.x;
  if (i >= n8) return;
  const float* in = (blockIdx.y == 0) ? i0 : (blockIdx.y == 1) ? i1 : (blockIdx.y == 2) ? i2 : i3;
  u16*        out = (blockIdx.y == 0) ? o0 : (blockIdx.y == 1) ? o1 : (blockIdx.y == 2) ? o2 : o3;
  float4 a = ((const float4*)in)[2*i];
  float4 b = ((const float4*)in)[2*i+1];
  u16x8 o;
  o[0]=f2bf(a.x); o[1]=f2bf(a.y); o[2]=f2bf(a.z); o[3]=f2bf(a.w);
  o[4]=f2bf(b.x); o[5]=f2bf(b.y); o[6]=f2bf(b.z); o[7]=f2bf(b.w);
  ((u16x8*)out)[i] = o;
}

// ---------------- GEMM: C[M,N] = A[M,K] * W[N,K]^T (m97-style 128x128 tile) ----------------
template<bool F32OUT>
__device__ __forceinline__ void gemm_body(const u16* __restrict__ A, const u16* __restrict__ W,
                                          void* __restrict__ Cv, int M, int N, int K) {
  __shared__ u16 Als[128*64];
  __shared__ u16 Bls[128*64];
  const int tid = threadIdx.x, lane = tid & 63, w = tid >> 6;
  const int wr = w >> 1, wc = w & 1;
  const int lr = lane & 15, lg = lane >> 4;
  const int m0 = blockIdx.x * 128, n0 = blockIdx.y * 128;
  f32x4 acc[4][4] = {};
  const int srow = lane >> 3;
  const int scol = (lane & 7) * 8;
  for (int k0 = 0; k0 < K; k0 += 64) {
    __syncthreads();
    #pragma unroll
    for (int c = 0; c < 4; ++c) {
      const int rb = w*32 + c*8;
      const u16* ga = A + (size_t)(m0 + rb + srow)*K + k0 + scol;
      const u16* gb = W + (size_t)(n0 + rb + srow)*K + k0 + scol;
      gl_lds16(ga, &Als[rb*64]);
      gl_lds16(gb, &Bls[rb*64]);
    }
    __syncthreads();
    #pragma unroll
    for (int ks = 0; ks < 2; ++ks) {
      bf16x8 am[4], bn[4];
      #pragma unroll
      for (int f = 0; f < 4; ++f) {
        am[f] = ldb8(&Als[(wr*64 + f*16 + lr)*64 + ks*32 + lg*8]);
        bn[f] = ldb8(&Bls[(wc*64 + f*16 + lr)*64 + ks*32 + lg*8]);
      }
      #pragma unroll
      for (int fm = 0; fm < 4; ++fm)
        #pragma unroll
        for (int fn = 0; fn < 4; ++fn)
          acc[fm][fn] = MFMA16x16x32(am[fm], bn[fn], acc[fm][fn]);
    }
  }
  #pragma unroll
  for (int fm = 0; fm < 4; ++fm)
    #pragma unroll
    for (int fn = 0; fn < 4; ++fn)
      #pragma unroll
      for (int r = 0; r < 4; ++r) {
        const int row = m0 + wr*64 + fm*16 + lg*4 + r;
        const int col = n0 + wc*64 + fn*16 + lr;
        if constexpr (F32OUT) ((float*)Cv)[(size_t)row*N + col] = acc[fm][fn][r];
        else                  ((u16*)Cv)[(size_t)row*N + col] = f2bf(acc[fm][fn][r]);
      }
}

__global__ void __launch_bounds__(256) gemm_qkv_kernel(const u16* __restrict__ X,
    const u16* __restrict__ Wq, const u16* __restrict__ Wk, const u16* __restrict__ Wv,
    u16* __restrict__ Qo, u16* __restrict__ Ko, u16* __restrict__ Vo) {
  const u16* W = (blockIdx.z == 0) ? Wq : (blockIdx.z == 1) ? Wk : Wv;
  u16*       C = (blockIdx.z == 0) ? Qo : (blockIdx.z == 1) ? Ko : Vo;
  gemm_body<false>(X, W, C, BL, D_MODEL, D_MODEL);
}

__global__ void __launch_bounds__(256) gemm_out_kernel(const u16* __restrict__ A, const u16* __restrict__ W,
                                                       float* __restrict__ C) {
  gemm_body<true>(A, W, C, BL, D_MODEL, D_MODEL);
}

// ---------------- RoPE (in-place on bf16 Q,K), folds 1/sqrt(dk)=0.125 into Q ----------------
__global__ void __launch_bounds__(256) rope_kernel(u16* __restrict__ Q, u16* __restrict__ K,
                                                   const int* __restrict__ pos) {
  int t = blockIdx.x * 256 + threadIdx.x;
  int i  = t & 31;
  int h  = (t >> 5) & 15;
  int bl = t >> 9;
  float fr = exp2f(-(float)i * 0.41524101186092f);
  float ang = (float)pos[bl] * fr;
  float sv, cv;
  sincosf(ang, &sv, &cv);
  size_t base = (size_t)bl * D_MODEL + h * DKH + 2*i;
  u32 qv = *(u32*)&Q[base];
  float qe = bf2f((u16)(qv & 0xFFFFu)), qo = bf2f((u16)(qv >> 16));
  float re = (qe*cv - qo*sv) * 0.125f;
  float ro = (qe*sv + qo*cv) * 0.125f;
  *(u32*)&Q[base] = (u32)f2bf(re) | ((u32)f2bf(ro) << 16);
  u32 kw = *(u32*)&K[base];
  float ke = bf2f((u16)(kw & 0xFFFFu)), ko = bf2f((u16)(kw >> 16));
  *(u32*)&K[base] = (u32)f2bf(ke*cv - ko*sv) | ((u32)f2bf(ke*sv + ko*cv) << 16);
}

// ---------------- causal flash attention ----------------
// 4 waves/block, 32 q-rows/wave (QBLK=128), KV tile 64, swapped QK^T on 32x32x16.
// S^T layout: col=lane&31=q-row (lane owns one q-row's scores), row(reg)=kp.
#define VSTR 72

__global__ void __launch_bounds__(256) attn_kernel(const u16* __restrict__ Q, const u16* __restrict__ K,
                                                   const u16* __restrict__ V, u16* __restrict__ O) {
  __shared__ u16 Kls[64*64];   // K tile, XOR-swizzled 16B slots: lds(row, s) = gmem(row, s^(row&7))
  __shared__ u16 Vt[64*VSTR];  // V^T tile: Vt[d][kp], pad 72 for 16B-aligned, bank-spread reads
  const int tid = threadIdx.x, lane = tid & 63, w = tid >> 6;
  const int l31 = lane & 31, h32 = lane >> 5;
  const int bh = blockIdx.y, b = bh >> 4, head = bh & 15;
  const int qt = (int)(gridDim.x - 1u - blockIdx.x);   // heavy tiles first (LPT)
  const int q0 = qt * 128;
  const int qw0 = q0 + w * 32;
  const size_t headoff = (size_t)b * SEQ * D_MODEL + head * DKH;
  const u16* Qb = Q + headoff;
  const u16* Kb = K + headoff;
  const u16* Vb = V + headoff;
  // Q fragments (B-operand): lane holds q-row qw0+l31, d = 16kc + 8*h32 + j
  bf16x8 qf[4];
  #pragma unroll
  for (int kc = 0; kc < 4; ++kc)
    qf[kc] = ldb8(Qb + (size_t)(qw0 + l31)*D_MODEL + kc*16 + h32*8);
  f32x16 o0 = {}, o1 = {};
  float mrun = -1e30f, lrun = 0.0f;
  const int ntiles = 2*(qt+1);
  const int srow  = lane >> 3;
  const int scol8 = ((lane & 7) ^ srow) * 8;   // pre-swizzled global source column
  for (int t = 0; t < ntiles; ++t) {
    const int kv0 = t * 64;
    __syncthreads();
    // --- stage K via global_load_lds (swizzled source, linear dest) ---
    #pragma unroll
    for (int i = 0; i < 2; ++i) {
      const int rb = (i*4 + w) * 8;
      gl_lds16(Kb + (size_t)(kv0 + rb + srow)*D_MODEL + scol8, &Kls[rb*64]);
    }
    // --- stage V^T: wave w owns d-rows (w+4i)*8..+7; lanes write consecutive kp (2-way, free) ---
    #pragma unroll
    for (int i = 0; i < 2; ++i) {
      const int d0 = (w + 4*i) * 8;
      u16x8 vv = *(const u16x8*)(Vb + (size_t)(kv0 + lane)*D_MODEL + d0);
      #pragma unroll
      for (int j = 0; j < 8; ++j) Vt[(d0 + j)*VSTR + lane] = vv[j];
    }
    __syncthreads();
    if (kv0 > qw0 + 31) continue;   // fully masked for this wave (barriers already passed)
    // --- QK^T swapped: S^T[kp][qrow] ---
    f32x16 s[2] = {};
    #pragma unroll
    for (int kc = 0; kc < 4; ++kc) {
      const int sl = ((2*kc + h32) ^ (l31 & 7)) * 8;
      bf16x8 k0 = ldb8(&Kls[(l31)*64 + sl]);
      bf16x8 k1 = ldb8(&Kls[(32 + l31)*64 + sl]);
      s[0] = MFMA32x32x16(k0, qf[kc], s[0]);
      s[1] = MFMA32x32x16(k1, qf[kc], s[1]);
    }
    // --- causal mask (diagonal tiles only) ---
    if (kv0 + 63 > qw0) {
      const int qrow = qw0 + l31;
      #pragma unroll
      for (int kb = 0; kb < 2; ++kb)
        #pragma unroll
        for (int r = 0; r < 16; ++r) {
          int kp = kv0 + kb*32 + (r&3) + 8*(r>>2) + 4*h32;
          if (kp > qrow) s[kb][r] = -1e30f;
        }
    }
    // --- online softmax, fully in-register (lane owns q-row l31) ---
    float mx = s[0][0];
    #pragma unroll
    for (int r = 1; r < 16; ++r) mx = fmaxf(mx, s[0][r]);
    #pragma unroll
    for (int r = 0; r < 16; ++r) mx = fmaxf(mx, s[1][r]);
    mx = fmaxf(mx, __shfl_xor(mx, 32, 64));
    const float mold = mrun;
    const float mnew = fmaxf(mold, mx);
    const float alpha = __expf(mold - mnew);
    mrun = mnew;
    float ps = 0.0f;
    #pragma unroll
    for (int kb = 0; kb < 2; ++kb)
      #pragma unroll
      for (int r = 0; r < 16; ++r) {
        float p = __expf(s[kb][r] - mnew);
        s[kb][r] = p;
        ps += p;
      }
    ps += __shfl_xor(ps, 32, 64);
    lrun = lrun * alpha + ps;
    // --- rescale O only when the running max actually grew ---
    if (__any(mx > mold)) {
      #pragma unroll
      for (int r = 0; r < 16; ++r) {
        float ar = __shfl(alpha, (r&3) + 8*(r>>2) + 4*h32, 64);
        o0[r] *= ar;
        o1[r] *= ar;
      }
    }
    // --- P fragments via bf16 pack + half-wave exchange; PV MFMA ---
    #pragma unroll
    for (int kb = 0; kb < 2; ++kb) {
      u32 pk[8], sw[8];
      #pragma unroll
      for (int k2 = 0; k2 < 8; ++k2) {
        pk[k2] = (u32)f2bf(s[kb][2*k2]) | ((u32)f2bf(s[kb][2*k2+1]) << 16);
        sw[k2] = (u32)__shfl_xor((int)pk[k2], 32, 64);
      }
      #pragma unroll
      for (int lm = 0; lm < 2; ++lm) {
        const int c = 2*kb + lm;
        u32x4 fw;
        fw[0] = h32 ? sw[4*lm+2] : pk[4*lm+0];
        fw[1] = h32 ? sw[4*lm+3] : pk[4*lm+1];
        fw[2] = h32 ? pk[4*lm+2] : sw[4*lm+0];
        fw[3] = h32 ? pk[4*lm+3] : sw[4*lm+1];
        bf16x8 pf = __builtin_bit_cast(bf16x8, fw);
        bf16x8 v0 = ldb8(&Vt[(l31)*VSTR + 16*c + 8*h32]);
        bf16x8 v1 = ldb8(&Vt[(32 + l31)*VSTR + 16*c + 8*h32]);
        o0 = MFMA32x32x16(pf, v0, o0);
        o1 = MFMA32x32x16(pf, v1, o1);
      }
    }
  }
  // --- epilogue: divide by row sum, write bf16 ---
  const float linv = 1.0f / lrun;
  u16* Ob = O + headoff;
  #pragma unroll
  for (int r = 0; r < 16; ++r) {
    const int rp = (r&3) + 8*(r>>2) + 4*h32;
    float li = __shfl(linv, rp, 64);
    const size_t grow = (size_t)(qw0 + rp) * D_MODEL;
    Ob[grow + l31]      = f2bf(o0[r] * li);
    Ob[grow + 32 + l31] = f2bf(o1[r] * li);
  }
}

// ---------------- launch ----------------
extern "C" void kernel_launch(void* const* d_in, const int* in_sizes, int n_in,
                              void* d_out, int out_size, void* d_ws, size_t ws_size,
                              hipStream_t stream) {
  const float* x  = (const float*)d_in[0];
  const int* pos  = (const int*)d_in[1];
  const float* WQ = (const float*)d_in[2];
  const float* WK = (const float*)d_in[3];
  const float* WV = (const float*)d_in[4];
  const float* WO = (const float*)d_in[5];
  u16* ws = (u16*)d_ws;
  const size_t NX = (size_t)BL * D_MODEL;
  const size_t NW = (size_t)D_MODEL * D_MODEL;
  u16* xb  = ws;
  u16* wqb = xb  + NX;
  u16* wkb = wqb + NW;
  u16* wvb = wkb + NW;
  u16* wob = wvb + NW;
  u16* qb  = wob + NW;
  u16* kb  = qb  + NX;
  u16* vb  = kb  + NX;
  u16* ab  = vb  + NX;

  cvt1_kernel<<<dim3((unsigned)(NX/8/256)), 256, 0, stream>>>(x, xb, (int)(NX/8));
  cvt4_kernel<<<dim3((unsigned)(NW/8/256), 4), 256, 0, stream>>>(WQ, WK, WV, WO, wqb, wkb, wvb, wob, (int)(NW/8));
  gemm_qkv_kernel<<<dim3(BL/128, D_MODEL/128, 3), 256, 0, stream>>>(xb, wqb, wkb, wvb, qb, kb, vb);
  rope_kernel<<<dim3(BL*512/256), 256, 0, stream>>>(qb, kb, pos);
  attn_kernel<<<dim3(16, BATCH*NHEAD), 256, 0, stream>>>(qb, kb, vb, ab);
  gemm_out_kernel<<<dim3(BL/128, D_MODEL/128), 256, 0, stream>>>(ab, wob, (float*)d_out);
}

// Round 4
// 174.201 us; speedup vs baseline: 1.3082x; 1.0375x over previous
//
#include <hip/hip_runtime.h>
#include <cstdint>
#include <cstddef>

#define D_MODEL 1024
#define NHEAD   16
#define DKH     64
#define BATCH   2
#define SEQ     2048
#define BL      (BATCH*SEQ)

typedef unsigned short u16;
typedef unsigned int   u32;
typedef __bf16 bf16_t;
typedef bf16_t bf16x8 __attribute__((ext_vector_type(8)));
typedef u16    u16x8  __attribute__((ext_vector_type(8)));
typedef u32    u32x4  __attribute__((ext_vector_type(4)));
typedef float  f32x4  __attribute__((ext_vector_type(4)));
typedef float  f32x16 __attribute__((ext_vector_type(16)));

__device__ __forceinline__ u16 f2bf(float f) {
  u32 u = __builtin_bit_cast(u32, f);
  u32 r = (u + 0x7FFFu + ((u >> 16) & 1u)) >> 16;
  return (u16)r;
}
__device__ __forceinline__ float bf2f(u16 h) {
  u32 u = ((u32)h) << 16;
  return __builtin_bit_cast(float, u);
}
__device__ __forceinline__ bf16x8 ldb8(const u16* p) {
  return __builtin_bit_cast(bf16x8, *(const u16x8*)p);
}
__device__ __forceinline__ void gl_lds16(const u16* g, u16* l) {
  __builtin_amdgcn_global_load_lds((const __attribute__((address_space(1))) void*)g,
                                   (__attribute__((address_space(3))) void*)l, 16, 0, 0);
}
#define MFMA16x16x32(a,b,c) __builtin_amdgcn_mfma_f32_16x16x32_bf16((a),(b),(c),0,0,0)
#define MFMA32x32x16(a,b,c) __builtin_amdgcn_mfma_f32_32x32x16_bf16((a),(b),(c),0,0,0)

// ---------------- fp32 -> bf16 converts ----------------
__global__ void __launch_bounds__(256) cvt1_kernel(const float* __restrict__ in, u16* __restrict__ out, int n8) {
  int i = blockIdx.x * 256 + threadIdx.x;
  if (i >= n8) return;
  float4 a = ((const float4*)in)[2*i];
  float4 b = ((const float4*)in)[2*i+1];
  u16x8 o;
  o[0]=f2bf(a.x); o[1]=f2bf(a.y); o[2]=f2bf(a.z); o[3]=f2bf(a.w);
  o[4]=f2bf(b.x); o[5]=f2bf(b.y); o[6]=f2bf(b.z); o[7]=f2bf(b.w);
  ((u16x8*)out)[i] = o;
}

__global__ void __launch_bounds__(256) cvt4_kernel(const float* __restrict__ i0, const float* __restrict__ i1,
                                                   const float* __restrict__ i2, const float* __restrict__ i3,
                                                   u16* __restrict__ o0, u16* __restrict__ o1,
                                                   u16* __restrict__ o2, u16* __restrict__ o3, int n8) {
  int i = blockIdx.x * 256 + threadIdx.x;
  if (i >= n8) return;
  const float* in = (blockIdx.y == 0) ? i0 : (blockIdx.y == 1) ? i1 : (blockIdx.y == 2) ? i2 : i3;
  u16*        out = (blockIdx.y == 0) ? o0 : (blockIdx.y == 1) ? o1 : (blockIdx.y == 2) ? o2 : o3;
  float4 a = ((const float4*)in)[2*i];
  float4 b = ((const float4*)in)[2*i+1];
  u16x8 o;
  o[0]=f2bf(a.x); o[1]=f2bf(a.y); o[2]=f2bf(a.z); o[3]=f2bf(a.w);
  o[4]=f2bf(b.x); o[5]=f2bf(b.y); o[6]=f2bf(b.z); o[7]=f2bf(b.w);
  ((u16x8*)out)[i] = o;
}

// ---------------- GEMM: C[M,N] = A[M,K] * W[N,K]^T (m97-style 128x128 tile) ----------------
template<bool F32OUT>
__device__ __forceinline__ void gemm_body(const u16* __restrict__ A, const u16* __restrict__ W,
                                          void* __restrict__ Cv, int M, int N, int K) {
  __shared__ u16 Als[128*64];
  __shared__ u16 Bls[128*64];
  const int tid = threadIdx.x, lane = tid & 63, w = tid >> 6;
  const int wr = w >> 1, wc = w & 1;
  const int lr = lane & 15, lg = lane >> 4;
  const int m0 = blockIdx.x * 128, n0 = blockIdx.y * 128;
  f32x4 acc[4][4] = {};
  const int srow = lane >> 3;
  const int scol = (lane & 7) * 8;
  for (int k0 = 0; k0 < K; k0 += 64) {
    __syncthreads();
    #pragma unroll
    for (int c = 0; c < 4; ++c) {
      const int rb = w*32 + c*8;
      const u16* ga = A + (size_t)(m0 + rb + srow)*K + k0 + scol;
      const u16* gb = W + (size_t)(n0 + rb + srow)*K + k0 + scol;
      gl_lds16(ga, &Als[rb*64]);
      gl_lds16(gb, &Bls[rb*64]);
    }
    __syncthreads();
    #pragma unroll
    for (int ks = 0; ks < 2; ++ks) {
      bf16x8 am[4], bn[4];
      #pragma unroll
      for (int f = 0; f < 4; ++f) {
        am[f] = ldb8(&Als[(wr*64 + f*16 + lr)*64 + ks*32 + lg*8]);
        bn[f] = ldb8(&Bls[(wc*64 + f*16 + lr)*64 + ks*32 + lg*8]);
      }
      #pragma unroll
      for (int fm = 0; fm < 4; ++fm)
        #pragma unroll
        for (int fn = 0; fn < 4; ++fn)
          acc[fm][fn] = MFMA16x16x32(am[fm], bn[fn], acc[fm][fn]);
    }
  }
  #pragma unroll
  for (int fm = 0; fm < 4; ++fm)
    #pragma unroll
    for (int fn = 0; fn < 4; ++fn)
      #pragma unroll
      for (int r = 0; r < 4; ++r) {
        const int row = m0 + wr*64 + fm*16 + lg*4 + r;
        const int col = n0 + wc*64 + fn*16 + lr;
        if constexpr (F32OUT) ((float*)Cv)[(size_t)row*N + col] = acc[fm][fn][r];
        else                  ((u16*)Cv)[(size_t)row*N + col] = f2bf(acc[fm][fn][r]);
      }
}

__global__ void __launch_bounds__(256) gemm_qkv_kernel(const u16* __restrict__ X,
    const u16* __restrict__ Wq, const u16* __restrict__ Wk, const u16* __restrict__ Wv,
    u16* __restrict__ Qo, u16* __restrict__ Ko, u16* __restrict__ Vo) {
  const u16* W = (blockIdx.z == 0) ? Wq : (blockIdx.z == 1) ? Wk : Wv;
  u16*       C = (blockIdx.z == 0) ? Qo : (blockIdx.z == 1) ? Ko : Vo;
  gemm_body<false>(X, W, C, BL, D_MODEL, D_MODEL);
}

__global__ void __launch_bounds__(256) gemm_out_kernel(const u16* __restrict__ A, const u16* __restrict__ W,
                                                       float* __restrict__ C) {
  gemm_body<true>(A, W, C, BL, D_MODEL, D_MODEL);
}

// ---------------- RoPE (in-place on bf16 Q,K) ----------------
// Q gets 0.125 * log2(e) folded in (softmax runs in exp2 domain).
__global__ void __launch_bounds__(256) rope_kernel(u16* __restrict__ Q, u16* __restrict__ K,
                                                   const int* __restrict__ pos) {
  int t = blockIdx.x * 256 + threadIdx.x;
  int i  = t & 31;
  int h  = (t >> 5) & 15;
  int bl = t >> 9;
  float fr = exp2f(-(float)i * 0.41524101186092f);
  float ang = (float)pos[bl] * fr;
  float sv, cv;
  sincosf(ang, &sv, &cv);
  const float QS = 0.18033688011112042f;   // 0.125 * log2(e)
  size_t base = (size_t)bl * D_MODEL + h * DKH + 2*i;
  u32 qv = *(u32*)&Q[base];
  float qe = bf2f((u16)(qv & 0xFFFFu)), qo = bf2f((u16)(qv >> 16));
  float re = (qe*cv - qo*sv) * QS;
  float ro = (qe*sv + qo*cv) * QS;
  *(u32*)&Q[base] = (u32)f2bf(re) | ((u32)f2bf(ro) << 16);
  u32 kw = *(u32*)&K[base];
  float ke = bf2f((u16)(kw & 0xFFFFu)), ko = bf2f((u16)(kw >> 16));
  *(u32*)&K[base] = (u32)f2bf(ke*cv - ko*sv) | ((u32)f2bf(ke*sv + ko*cv) << 16);
}

// ---------------- causal flash attention ----------------
// Block = (bh, q-tile pair {p, 15-p}) -> constant 34 KV-tiles/block, 256 blocks (1/CU).
// 4 waves x 32 q-rows. Swapped QK^T on 32x32x16: lane owns q-row (col=lane&31).
// Double-buffered K (XOR-swizzled via gl_lds) and V^T staging, 1 barrier/tile.
#define VSTR 72

__device__ __forceinline__ void attn_pass(
    const int q0, const int ntiles,
    const u16* __restrict__ Qb, const u16* __restrict__ Kb,
    const u16* __restrict__ Vb, u16* __restrict__ Ob,
    u16* __restrict__ Kls, u16* __restrict__ Vt,
    const int lane, const int w)
{
  const int l31 = lane & 31, h32 = lane >> 5;
  const int qw0 = q0 + w * 32;
  const int srow  = lane >> 3;
  const int scol8 = ((lane & 7) ^ srow) * 8;
  bf16x8 qf[4];
  #pragma unroll
  for (int kc = 0; kc < 4; ++kc)
    qf[kc] = ldb8(Qb + (size_t)(qw0 + l31)*D_MODEL + kc*16 + h32*8);
  f32x16 o0 = {}, o1 = {};
  float mrun = -1e30f, lrun = 0.0f;

  __syncthreads();   // protect prior pass's last reads before we overwrite buf 0
  // ---- prologue: stage tile 0 into buffer 0 ----
  {
    #pragma unroll
    for (int i = 0; i < 2; ++i) {
      const int rb = (i*4 + w) * 8;
      gl_lds16(Kb + (size_t)(rb + srow)*D_MODEL + scol8, &Kls[rb*64]);
    }
    u16x8 a = *(const u16x8*)(Vb + (size_t)lane*D_MODEL + w*8);
    u16x8 c = *(const u16x8*)(Vb + (size_t)lane*D_MODEL + (w+4)*8);
    #pragma unroll
    for (int j = 0; j < 8; ++j) Vt[(w*8 + j)*VSTR + lane] = a[j];
    #pragma unroll
    for (int j = 0; j < 8; ++j) Vt[((w+4)*8 + j)*VSTR + lane] = c[j];
  }
  __syncthreads();

  for (int t = 0; t < ntiles; ++t) {
    const int buf = t & 1, nbuf = buf ^ 1;
    const int kv0 = t * 64;
    const bool pf = (t + 1 < ntiles);
    u16x8 vr0, vr1;
    if (pf) {   // issue next-tile loads early (K direct-to-LDS, V to regs)
      const int kn = kv0 + 64;
      #pragma unroll
      for (int i = 0; i < 2; ++i) {
        const int rb = (i*4 + w) * 8;
        gl_lds16(Kb + (size_t)(kn + rb + srow)*D_MODEL + scol8, &Kls[nbuf*4096 + rb*64]);
      }
      vr0 = *(const u16x8*)(Vb + (size_t)(kn + lane)*D_MODEL + w*8);
      vr1 = *(const u16x8*)(Vb + (size_t)(kn + lane)*D_MODEL + (w+4)*8);
    }
    if (kv0 <= qw0 + 31) {   // wave-uniform: compute tile t
      const u16* Kb0 = &Kls[buf*4096];
      const u16* Vt0 = &Vt[buf*(64*VSTR)];
      f32x16 s[2] = {};
      #pragma unroll
      for (int kc = 0; kc < 4; ++kc) {
        const int sl = ((2*kc + h32) ^ (l31 & 7)) * 8;
        bf16x8 k0 = ldb8(&Kb0[(l31)*64 + sl]);
        bf16x8 k1 = ldb8(&Kb0[(32 + l31)*64 + sl]);
        s[0] = MFMA32x32x16(k0, qf[kc], s[0]);
        s[1] = MFMA32x32x16(k1, qf[kc], s[1]);
      }
      if (kv0 + 63 > qw0) {   // diagonal: causal mask
        const int qrow = qw0 + l31;
        #pragma unroll
        for (int kb = 0; kb < 2; ++kb)
          #pragma unroll
          for (int r = 0; r < 16; ++r) {
            int kp = kv0 + kb*32 + (r&3) + 8*(r>>2) + 4*h32;
            if (kp > qrow) s[kb][r] = -1e30f;
          }
      }
      // online softmax in exp2 domain, lane owns q-row l31
      float mx = s[0][0];
      #pragma unroll
      for (int r = 1; r < 16; ++r) mx = fmaxf(mx, s[0][r]);
      #pragma unroll
      for (int r = 0; r < 16; ++r) mx = fmaxf(mx, s[1][r]);
      mx = fmaxf(mx, __shfl_xor(mx, 32, 64));
      if (!__all(mx - mrun <= 8.0f)) {   // defer-max: rescale only on real growth
        const float mnew = fmaxf(mrun, mx);
        const float al = exp2f(mrun - mnew);
        #pragma unroll
        for (int r = 0; r < 16; ++r) {
          float ar = __shfl(al, (r&3) + 8*(r>>2) + 4*h32, 64);
          o0[r] *= ar;
          o1[r] *= ar;
        }
        lrun *= al;
        mrun = mnew;
      }
      float ps = 0.0f;
      #pragma unroll
      for (int kb = 0; kb < 2; ++kb)
        #pragma unroll
        for (int r = 0; r < 16; ++r) {
          float p = exp2f(s[kb][r] - mrun);
          s[kb][r] = p;
          ps += p;
        }
      ps += __shfl_xor(ps, 32, 64);
      lrun += ps;
      // P fragments via bf16 pack + half-wave exchange; PV MFMA
      #pragma unroll
      for (int kb = 0; kb < 2; ++kb) {
        u32 pk[8], sw[8];
        #pragma unroll
        for (int k2 = 0; k2 < 8; ++k2) {
          pk[k2] = (u32)f2bf(s[kb][2*k2]) | ((u32)f2bf(s[kb][2*k2+1]) << 16);
          sw[k2] = (u32)__shfl_xor((int)pk[k2], 32, 64);
        }
        #pragma unroll
        for (int lm = 0; lm < 2; ++lm) {
          const int c = 2*kb + lm;
          u32x4 fw;
          fw[0] = h32 ? sw[4*lm+2] : pk[4*lm+0];
          fw[1] = h32 ? sw[4*lm+3] : pk[4*lm+1];
          fw[2] = h32 ? pk[4*lm+2] : sw[4*lm+0];
          fw[3] = h32 ? pk[4*lm+3] : sw[4*lm+1];
          bf16x8 pfr = __builtin_bit_cast(bf16x8, fw);
          bf16x8 v0 = ldb8(&Vt0[(l31)*VSTR + 16*c + 8*h32]);
          bf16x8 v1 = ldb8(&Vt0[(32 + l31)*VSTR + 16*c + 8*h32]);
          o0 = MFMA32x32x16(pfr, v0, o0);
          o1 = MFMA32x32x16(pfr, v1, o1);
        }
      }
    }
    if (pf) {   // write prefetched V^T into the other buffer
      u16* Vtn = &Vt[nbuf*(64*VSTR)];
      #pragma unroll
      for (int j = 0; j < 8; ++j) Vtn[(w*8 + j)*VSTR + lane] = vr0[j];
      #pragma unroll
      for (int j = 0; j < 8; ++j) Vtn[((w+4)*8 + j)*VSTR + lane] = vr1[j];
    }
    __syncthreads();
  }
  // epilogue
  const float linv = 1.0f / lrun;
  #pragma unroll
  for (int r = 0; r < 16; ++r) {
    const int rp = (r&3) + 8*(r>>2) + 4*h32;
    float li = __shfl(linv, rp, 64);
    const size_t grow = (size_t)(qw0 + rp) * D_MODEL;
    Ob[grow + l31]      = f2bf(o0[r] * li);
    Ob[grow + 32 + l31] = f2bf(o1[r] * li);
  }
}

__global__ void __launch_bounds__(256) attn_kernel(const u16* __restrict__ Q, const u16* __restrict__ K,
                                                   const u16* __restrict__ V, u16* __restrict__ O) {
  __shared__ u16 Kls[2][64*64];
  __shared__ u16 Vt[2][64*VSTR];
  const int tid = threadIdx.x, lane = tid & 63, w = tid >> 6;
  const int p = blockIdx.x;                     // 0..7: q-tile pair {p, 15-p}
  const int bh = blockIdx.y, b = bh >> 4, head = bh & 15;
  const size_t headoff = (size_t)b * SEQ * D_MODEL + head * DKH;
  const u16* Qb = Q + headoff;
  const u16* Kb = K + headoff;
  const u16* Vb = V + headoff;
  u16* Ob = (u16*)O + headoff;
  attn_pass(p*128,        2*(p+1),  Qb, Kb, Vb, Ob, &Kls[0][0], &Vt[0][0], lane, w);
  attn_pass((15-p)*128,   2*(16-p), Qb, Kb, Vb, Ob, &Kls[0][0], &Vt[0][0], lane, w);
}

// ---------------- launch ----------------
extern "C" void kernel_launch(void* const* d_in, const int* in_sizes, int n_in,
                              void* d_out, int out_size, void* d_ws, size_t ws_size,
                              hipStream_t stream) {
  const float* x  = (const float*)d_in[0];
  const int* pos  = (const int*)d_in[1];
  const float* WQ = (const float*)d_in[2];
  const float* WK = (const float*)d_in[3];
  const float* WV = (const float*)d_in[4];
  const float* WO = (const float*)d_in[5];
  u16* ws = (u16*)d_ws;
  const size_t NX = (size_t)BL * D_MODEL;
  const size_t NW = (size_t)D_MODEL * D_MODEL;
  u16* xb  = ws;
  u16* wqb = xb  + NX;
  u16* wkb = wqb + NW;
  u16* wvb = wkb + NW;
  u16* wob = wvb + NW;
  u16* qb  = wob + NW;
  u16* kb  = qb  + NX;
  u16* vb  = kb  + NX;
  u16* ab  = vb  + NX;

  cvt1_kernel<<<dim3((unsigned)(NX/8/256)), 256, 0, stream>>>(x, xb, (int)(NX/8));
  cvt4_kernel<<<dim3((unsigned)(NW/8/256), 4), 256, 0, stream>>>(WQ, WK, WV, WO, wqb, wkb, wvb, wob, (int)(NW/8));
  gemm_qkv_kernel<<<dim3(BL/128, D_MODEL/128, 3), 256, 0, stream>>>(xb, wqb, wkb, wvb, qb, kb, vb);
  rope_kernel<<<dim3(BL*512/256), 256, 0, stream>>>(qb, kb, pos);
  attn_kernel<<<dim3(8, BATCH*NHEAD), 256, 0, stream>>>(qb, kb, vb, ab);
  gemm_out_kernel<<<dim3(BL/128, D_MODEL/128), 256, 0, stream>>>(ab, wob, (float*)d_out);
}